// Round 1
// baseline (332.553 us; speedup 1.0000x reference)
//
#include <hip/hip_runtime.h>
#include <hip/hip_bf16.h>

// Problem constants (MultiAgentSEPSNetwork): A=8 agents, E=4096, O=256,
// H1=H2=1024, H3=512, S=4 nets. M = A*E = 32768 rows.
// Only the seps_idx-selected net per agent is needed (reference computes all S
// then gathers -> 4x redundant FLOPs we skip).

typedef unsigned short u16;
typedef __bf16 bf16x8 __attribute__((ext_vector_type(8)));
typedef float floatx4 __attribute__((ext_vector_type(4)));

__device__ __forceinline__ u16 f2bf(float f) {
    union { float f; unsigned int u; } v; v.f = f;
    unsigned int u = v.u;
    unsigned int r = (u + 0x7FFFu + ((u >> 16) & 1u)) >> 16;
    return (u16)r;
}

// global -> LDS direct DMA, 16 bytes/lane. LDS dest must be wave-uniform base;
// HW writes base + lane*16.
__device__ __forceinline__ void load16(const void* g, void* l) {
    __builtin_amdgcn_global_load_lds(
        (const __attribute__((address_space(1))) void*)(unsigned long long)g,
        (__attribute__((address_space(3))) void*)(unsigned int)(unsigned long long)l,
        16, 0, 0);
}

// ---------------- conversion kernels ----------------

__global__ void convert_f32_bf16(const float* __restrict__ src,
                                 u16* __restrict__ dst, int n) {
    int i = (blockIdx.x * blockDim.x + threadIdx.x) * 4;
    if (i < n) {
        float4 v = *(const float4*)(src + i);
        ushort4 o;
        o.x = f2bf(v.x); o.y = f2bf(v.y); o.z = f2bf(v.z); o.w = f2bf(v.w);
        *(ushort4*)(dst + i) = o;
    }
}

// [S][K][N] f32 -> [S][N][K] bf16 (weight transpose so B-fragment k is
// contiguous in LDS -> ds_read_b128). 32x32 LDS tile, +1 pad.
__global__ void transpose_to_bf16(const float* __restrict__ src,
                                  u16* __restrict__ dst, int K, int N) {
    __shared__ float tile[32][33];
    int s = blockIdx.z;
    src += (size_t)s * K * N;
    dst += (size_t)s * N * K;
    int n0 = blockIdx.x * 32, k0 = blockIdx.y * 32;
    int tx = threadIdx.x, ty = threadIdx.y;
#pragma unroll
    for (int j = 0; j < 32; j += 8)
        tile[ty + j][tx] = src[(size_t)(k0 + ty + j) * N + (n0 + tx)];
    __syncthreads();
#pragma unroll
    for (int j = 0; j < 32; j += 8)
        dst[(size_t)(n0 + ty + j) * K + (k0 + tx)] = f2bf(tile[tx][ty + j]);
}

// ---------------- grouped GEMM (m97 structure) ----------------
// C[m0+.., n0+..] = act(A[M,K] @ Wt[s][N,K]^T + bias[s][N])
// 128x128 tile, BK=32, 256 threads = 4 waves (2x2), 64x64 per wave,
// 16x16x32 bf16 MFMA, 4x4 acc tiles per wave.
template <int K, int N, bool RELU, bool OUT_BF16>
__global__ __launch_bounds__(256) void gemm_mlp(
    const u16* __restrict__ Amat, const u16* __restrict__ Wt,
    const float* __restrict__ bias, const int* __restrict__ seps,
    void* __restrict__ outp) {
    constexpr int BM = 128, BN = 128, BK = 32;
    __shared__ u16 smA[BM * BK];   // [m][k], 64 B rows, no pad (global_load_lds)
    __shared__ u16 smB[BN * BK];   // [n][k]

    const int tid = threadIdx.x;
    const int wave = tid >> 6, lane = tid & 63;
    const int wm = wave >> 1, wn = wave & 1;
    const int quad = lane >> 4, l16 = lane & 15;

    const int m0 = blockIdx.x * BM;
    const int n0 = blockIdx.y * BN;
    const int s = seps[m0 >> 12];               // 4096 rows per agent
    const u16* Ab = Amat + (size_t)m0 * K;
    const u16* Bb = Wt + (size_t)s * N * K + (size_t)n0 * K;

    // staging coords: each wave issues 2 A-insts + 2 B-insts per K-step,
    // each inst covers 16 rows x 32 k (1024 B, lane i -> chunkbase + i*16 B)
    const int srow0 = wave * 32 + (lane >> 2);  // chunk j adds 16
    const int scol = (lane & 3) * 8;

    floatx4 acc[4][4];
#pragma unroll
    for (int i = 0; i < 4; ++i)
#pragma unroll
        for (int j = 0; j < 4; ++j) acc[i][j] = (floatx4){0.f, 0.f, 0.f, 0.f};

    for (int k0 = 0; k0 < K; k0 += BK) {
#pragma unroll
        for (int j = 0; j < 2; ++j) {
            const int r = srow0 + j * 16;
            load16(Ab + (size_t)r * K + k0 + scol, &smA[(wave * 2 + j) * 16 * BK]);
            load16(Bb + (size_t)r * K + k0 + scol, &smB[(wave * 2 + j) * 16 * BK]);
        }
        __syncthreads();   // drains vmcnt for global_load_lds, then barrier

        bf16x8 af[4], bfv[4];
#pragma unroll
        for (int t = 0; t < 4; ++t) {
            af[t]  = *(const bf16x8*)&smA[(wm * 64 + t * 16 + l16) * BK + quad * 8];
            bfv[t] = *(const bf16x8*)&smB[(wn * 64 + t * 16 + l16) * BK + quad * 8];
        }
#pragma unroll
        for (int mt = 0; mt < 4; ++mt)
#pragma unroll
            for (int nt = 0; nt < 4; ++nt)
                acc[mt][nt] = __builtin_amdgcn_mfma_f32_16x16x32_bf16(
                    af[mt], bfv[nt], acc[mt][nt], 0, 0, 0);
        __syncthreads();
    }

    // epilogue: C/D layout col=lane&15, row=quad*4+reg
#pragma unroll
    for (int nt = 0; nt < 4; ++nt) {
        const int gcol = n0 + wn * 64 + nt * 16 + l16;
        const float bv = bias[s * N + gcol];
#pragma unroll
        for (int mt = 0; mt < 4; ++mt) {
            const int grow = m0 + wm * 64 + mt * 16 + quad * 4;
#pragma unroll
            for (int r2 = 0; r2 < 4; ++r2) {
                float v = acc[mt][nt][r2] + bv;
                if (RELU) v = fmaxf(v, 0.0f);
                if (OUT_BF16)
                    ((u16*)outp)[(size_t)(grow + r2) * N + gcol] = f2bf(v);
                else
                    ((float*)outp)[(size_t)(grow + r2) * N + gcol] = v;
            }
        }
    }
}

extern "C" void kernel_launch(void* const* d_in, const int* in_sizes, int n_in,
                              void* d_out, int out_size, void* d_ws, size_t ws_size,
                              hipStream_t stream) {
    const float* x  = (const float*)d_in[0];
    const float* W1 = (const float*)d_in[1];
    const float* b1 = (const float*)d_in[2];
    const float* W2 = (const float*)d_in[3];
    const float* b2 = (const float*)d_in[4];
    const float* W3 = (const float*)d_in[5];
    const float* b3 = (const float*)d_in[6];
    const int* seps = (const int*)d_in[7];

    char* ws = (char*)d_ws;
    u16* w1t = (u16*)(ws);                    //  2 MB: [4][1024][256]
    u16* w2t = (u16*)(ws + (2ull << 20));     //  8 MB: [4][1024][1024]
    u16* w3t = (u16*)(ws + (10ull << 20));    //  4 MB: [4][512][1024]
    u16* xb  = (u16*)(ws + (14ull << 20));    // 16 MB: [32768][256]
    u16* h1  = (u16*)(ws + (30ull << 20));    // 64 MB: [32768][1024]
    u16* h2  = (u16*)(ws + (94ull << 20));    // 64 MB: [32768][1024]  (total 158 MB)

    // x -> bf16 (8,388,608 elems, 4/thread)
    convert_f32_bf16<<<8192, 256, 0, stream>>>(x, xb, 8388608);
    // weights -> transposed bf16 [S][N][K]
    transpose_to_bf16<<<dim3(32, 8, 4),  dim3(32, 8), 0, stream>>>(W1, w1t, 256, 1024);
    transpose_to_bf16<<<dim3(32, 32, 4), dim3(32, 8), 0, stream>>>(W2, w2t, 1024, 1024);
    transpose_to_bf16<<<dim3(16, 32, 4), dim3(32, 8), 0, stream>>>(W3, w3t, 1024, 512);

    // L1: [32768,256]@[256,1024] +b1, relu -> h1 (bf16)
    gemm_mlp<256, 1024, true, true><<<dim3(256, 8), 256, 0, stream>>>(xb, w1t, b1, seps, h1);
    // L2: [32768,1024]@[1024,1024] +b2, relu -> h2 (bf16)
    gemm_mlp<1024, 1024, true, true><<<dim3(256, 8), 256, 0, stream>>>(h1, w2t, b2, seps, h2);
    // L3: [32768,1024]@[1024,512] +b3 -> out (f32)
    gemm_mlp<1024, 512, false, false><<<dim3(256, 4), 256, 0, stream>>>(h2, w3t, b3, seps, d_out);
}